// Round 5
// baseline (353.344 us; speedup 1.0000x reference)
//
#include <hip/hip_runtime.h>
#include <hip/hip_cooperative_groups.h>
#include <hip/hip_bf16.h>
#include <cstdint>
#include <cstddef>

namespace cg = cooperative_groups;

// ---------------- ws layout (float slots) ----------------
#define OFF_P     0            // 2048*32 f32
#define OFF_QB    65536        // 2048*32 f32
#define OFF_TDOT  131072       // 2048 f32
#define OFF_COLSQ 133120       // 2048 f32
#define OFF_ZT    135168       // 4*10*512 f32
#define OFF_G1B   155648       // 2048*64 bf16
#define OFF_AMXB  221184       // 4*512*512 bf16
#define OFF_WBT   745472       // 4*512*512 bf16
#define OFF_ABF   1269760      // 4*512*512 bf16
#define OFF_G1T   1794048      // 4*64*512 bf16

typedef __attribute__((ext_vector_type(8))) short short8;
typedef __attribute__((ext_vector_type(8))) unsigned short ushort8;
typedef __attribute__((ext_vector_type(4))) float f32x4;

__device__ inline unsigned short f2bf(float f) {
    unsigned u = __builtin_bit_cast(unsigned, f);
    unsigned r = u + 0x7FFFu + ((u >> 16) & 1u);
    return (unsigned short)(r >> 16);
}
__device__ inline float bf2f(unsigned short s) {
    unsigned u = ((unsigned)s) << 16;
    return __builtin_bit_cast(float, u);
}
__device__ inline float tanh_fast(float x) {
    return 1.f - 2.f/(__expf(2.f*x) + 1.f);
}

struct MP {
    const float *x,*W_ih,*W_hh,*b_ih,*b_hh,*W1,*b1,*W2,*V,*bv,*Wb,*wb;
    const float *conv_w,*conv_b,*convl_w,*convl_b,*gc1_w,*gc1_b,*gc2_w,*gc2_b,*out_w,*out_b,*adj;
    float *p,*qb,*tdot,*colsq,*zT,*out;
    unsigned short *G1bf,*amxB,*WbT,*Abf,*G1T;
};

union SMem {
    struct { float h[4][64]; float xt[4][20]; float rl[4][30]; } p1;
    struct { float p_sh[32*36]; float q_sh[32*36]; float v_sh[32]; float sq[32*17]; } p2;
    struct { float tile[64][68]; } p3a;
    struct { unsigned short ttile[64*72]; } p3b;
    struct { unsigned short As[16*520]; float xg[16][68]; } p5;
};

__global__ __launch_bounds__(256, 2) void mega(MP g)
{
    cg::grid_group grid = cg::this_grid();
    __shared__ __align__(16) SMem sm;
    const int tid  = threadIdx.x;
    const int bid  = blockIdx.x;          // 0..511
    const int w    = tid >> 6;
    const int lane = tid & 63;

    // ================= Phase 1: RNN + p/q + convs + G1 + tdot (+ zero colsq) =================
    // All LDS wave-private -> no __syncthreads in this phase.
    {
        int s = bid * 4 + w;
        int b = s >> 9, m = s & 511;

        if (bid < 8) g.colsq[bid * 256 + tid] = 0.f;

        if (lane < 20) sm.p1.xt[w][lane] = g.x[(b*20 + lane)*512 + m];

        float wrow[64];
        const float* wr = g.W_hh + lane*64;
        #pragma unroll
        for (int k4 = 0; k4 < 16; ++k4) {
            float4 v = reinterpret_cast<const float4*>(wr)[k4];
            wrow[4*k4+0]=v.x; wrow[4*k4+1]=v.y; wrow[4*k4+2]=v.z; wrow[4*k4+3]=v.w;
        }
        float wih = g.W_ih[lane], bih = g.b_ih[lane], bhh = g.b_hh[lane];
        sm.p1.h[w][lane] = 0.f;
        float h = 0.f;

        // convs first (independent of h)
        if (lane < 10) {
            float acc = g.conv_b[lane];
            #pragma unroll
            for (int t = 0; t < 20; ++t) acc += g.conv_w[lane*20+t]*sm.p1.xt[w][t];
            sm.p1.rl[w][3*lane] = fmaxf(acc, 0.f);
        } else if (lane < 30) {
            int idx = lane-10, j = idx>>1, oo = idx&1;
            float acc = g.convl_b[j];
            #pragma unroll
            for (int t = 0; t < 10; ++t) acc += g.convl_w[j*10+t]*sm.p1.xt[w][oo+2*t];
            sm.p1.rl[w][3*j+1+oo] = fmaxf(acc, 0.f);
        }

        for (int t = 0; t < 20; ++t) {
            float acc = sm.p1.xt[w][t]*wih + bih + bhh;
            #pragma unroll
            for (int k = 0; k < 64; ++k) acc += wrow[k]*sm.p1.h[w][k];
            h = tanh_fast(acc);
            sm.p1.h[w][lane] = h;
        }

        float td = h * g.out_w[10 + lane];
        #pragma unroll
        for (int off = 32; off; off >>= 1) td += __shfl_down(td, off);
        if (lane == 0) g.tdot[s] = td + g.out_b[0];

        if (lane < 32) {
            const float* w1r = g.W1 + lane*64;
            float acc = 0.f;
            #pragma unroll
            for (int k = 0; k < 64; ++k) acc += w1r[k]*sm.p1.h[w][k];
            g.p[s*32 + lane] = acc;
        } else {
            int i = lane - 32;
            const float* w2r = g.W2 + i*64;
            float acc = 0.f;
            #pragma unroll
            for (int k = 0; k < 64; ++k) acc += w2r[k]*sm.p1.h[w][k];
            g.qb[s*32 + i] = acc + g.b1[i];
        }

        float gg = 0.f;
        #pragma unroll
        for (int t = 0; t < 30; ++t) gg += sm.p1.rl[w][t]*g.gc1_w[t*64 + lane];
        g.G1bf[s*64 + lane] = f2bf(gg);
    }
    grid.sync();

    // ================= Phase 2: amxB = bf16(V.elu(p_i+qb_j)+bv); colsq =================
    for (int tile = bid; tile < 1024; tile += 512) {
        __syncthreads();   // protect LDS reuse across iterations/phases
        int b = tile >> 8, rem = tile & 255;
        int i0 = (rem >> 4) << 5, j0 = (rem & 15) << 5;
        {
            int r = tid >> 3, c4 = (tid & 7)*4;
            *(float4*)&sm.p2.p_sh[r*36 + c4] = *(const float4*)(g.p  + (size_t)(b*512 + i0 + r)*32 + c4);
            *(float4*)&sm.p2.q_sh[r*36 + c4] = *(const float4*)(g.qb + (size_t)(b*512 + j0 + r)*32 + c4);
        }
        if (tid < 32) sm.p2.v_sh[tid] = g.V[tid];
        __syncthreads();

        int ti = tid >> 4, tj = tid & 15;
        float bv0 = g.bv[0];
        float a00 = bv0, a01 = bv0, a10 = bv0, a11 = bv0;
        #pragma unroll
        for (int h = 0; h < 32; ++h) {
            float p0 = sm.p2.p_sh[ti*36 + h], p1 = sm.p2.p_sh[(ti+16)*36 + h];
            float q0 = sm.p2.q_sh[tj*36 + h], q1 = sm.p2.q_sh[(tj+16)*36 + h];
            float vh = sm.p2.v_sh[h];
            float x00 = p0+q0, x01 = p0+q1, x10 = p1+q0, x11 = p1+q1;
            float e00 = x00 > 0.f ? x00 : __expf(x00)-1.f;
            float e01 = x01 > 0.f ? x01 : __expf(x01)-1.f;
            float e10 = x10 > 0.f ? x10 : __expf(x10)-1.f;
            float e11 = x11 > 0.f ? x11 : __expf(x11)-1.f;
            a00 += vh*e00; a01 += vh*e01; a10 += vh*e10; a11 += vh*e11;
        }
        size_t base0 = ((size_t)(b*512 + i0 + ti))*512 + j0;
        size_t base1 = ((size_t)(b*512 + i0 + ti + 16))*512 + j0;
        g.amxB[base0 + tj]      = f2bf(a00);
        g.amxB[base0 + tj + 16] = f2bf(a01);
        g.amxB[base1 + tj]      = f2bf(a10);
        g.amxB[base1 + tj + 16] = f2bf(a11);

        sm.p2.sq[tj*17 + ti]      = a00*a00 + a10*a10;
        sm.p2.sq[(tj+16)*17 + ti] = a01*a01 + a11*a11;
        __syncthreads();
        if (tid < 32) {
            float ssum = 0.f;
            #pragma unroll
            for (int r = 0; r < 16; ++r) ssum += sm.p2.sq[tid*17 + r];
            atomicAdd(&g.colsq[b*512 + j0 + tid], ssum);
        }
    }
    grid.sync();

    // ================= Phase 3: WbT scale (blocks 0..63) / G1T transpose (64..71) =================
    if (bid < 64) {
        int j0 = (bid & 7)*64, k0 = (bid >> 3)*64;
        #pragma unroll
        for (int q = 0; q < 4; ++q) {
            int kr = (tid>>4) + 16*q;
            int jc = (tid&15)*4;
            *(float4*)&sm.p3a.tile[kr][jc] = *(const float4*)(g.Wb + (size_t)(k0+kr)*512 + j0 + jc);
        }
        __syncthreads();
        int jl = tid>>2, kc = (tid&3)*16;
        int j = j0 + jl;
        for (int b = 0; b < 4; ++b) {
            ushort8 v0, v1;
            #pragma unroll
            for (int kk = 0; kk < 8; ++kk) {
                float inv = 1.f/fmaxf(sqrtf(g.colsq[b*512 + k0+kc+kk]), 1e-12f);
                v0[kk] = f2bf(sm.p3a.tile[kc+kk][jl] * inv);
            }
            #pragma unroll
            for (int kk = 0; kk < 8; ++kk) {
                float inv = 1.f/fmaxf(sqrtf(g.colsq[b*512 + k0+kc+8+kk]), 1e-12f);
                v1[kk] = f2bf(sm.p3a.tile[kc+8+kk][jl] * inv);
            }
            unsigned short* dst = g.WbT + ((size_t)(b*512 + j))*512 + k0 + kc;
            *(ushort8*)dst = v0;
            *(ushort8*)(dst+8) = v1;
        }
    } else if (bid < 72) {
        int bb = bid - 64;
        int b = bb >> 1;
        int j0base = (bb & 1) * 256;
        for (int chunk = 0; chunk < 4; ++chunk) {
            int j0 = j0base + chunk*64;
            {
                int jr = tid >> 2, c0 = (tid & 3)*16;
                const unsigned short* src = g.G1bf + ((size_t)(b*512 + j0 + jr))*64 + c0;
                *(short8*)&sm.p3b.ttile[jr*72 + c0]     = *(const short8*)src;
                *(short8*)&sm.p3b.ttile[jr*72 + c0 + 8] = *(const short8*)(src + 8);
            }
            __syncthreads();
            {
                int c = tid >> 2, jc = (tid & 3)*16;
                ushort8 v0, v1;
                #pragma unroll
                for (int q = 0; q < 8; ++q) v0[q] = sm.p3b.ttile[(jc+q)*72 + c];
                #pragma unroll
                for (int q = 0; q < 8; ++q) v1[q] = sm.p3b.ttile[(jc+8+q)*72 + c];
                unsigned short* dst = g.G1T + ((size_t)(b*64 + c))*512 + j0 + jc;
                *(ushort8*)dst = v0;
                *(ushort8*)(dst+8) = v1;
            }
            __syncthreads();
        }
    }
    grid.sync();

    // ================= Phase 4: gate matmul, 32x16 tile per wave, direct-from-L2 =================
    {
        int wg = bid*4 + w;                 // 0..2047 == tile id
        int b  = wg >> 9;
        int r  = wg & 511;
        int i0 = (r >> 5) * 32, j0 = (r & 31) * 16;
        f32x4 acc[2] = {};

        const unsigned short* abase = g.amxB + ((size_t)(b*512 + i0 + (lane&15)))*512 + (lane>>4)*8;
        const unsigned short* bbase = g.WbT  + ((size_t)(b*512 + j0 + (lane&15)))*512 + (lane>>4)*8;

        #pragma unroll 4
        for (int k0 = 0; k0 < 512; k0 += 32) {
            short8 a0 = *(const short8*)(abase + k0);
            short8 a1 = *(const short8*)(abase + 16*512 + k0);
            short8 b0 = *(const short8*)(bbase + k0);
            acc[0] = __builtin_amdgcn_mfma_f32_16x16x32_bf16(a0, b0, acc[0],0,0,0);
            acc[1] = __builtin_amdgcn_mfma_f32_16x16x32_bf16(a1, b0, acc[1],0,0,0);
        }

        float wbs = g.wb[0];
        int j = j0 + (lane&15);
        float inv = 1.f/fmaxf(sqrtf(g.colsq[b*512 + j]), 1e-12f);
        #pragma unroll
        for (int fi = 0; fi < 2; ++fi)
        #pragma unroll
        for (int rr = 0; rr < 4; ++rr) {
            int i = i0 + fi*16 + (lane>>4)*4 + rr;
            float S = acc[fi][rr] + wbs;
            float c = 1.f/(1.f + __expf(-S));
            float aN = bf2f(g.amxB[((size_t)(b*512)+i)*512 + j]) * inv;
            g.Abf[((size_t)(b*512)+i)*512 + j] = f2bf(g.adj[i*512+j]*c + aN*(1.f - c));
        }
    }
    grid.sync();

    // ================= Phase 5: xg = relu(Abf@G1 + gc1_b); zT = xg@gc2_w (blocks 0..127) =================
    if (bid < 128) {
        int b = bid >> 5, i0 = (bid & 31)*16;
        {
            int r = tid >> 4, seg = (tid & 15)*32;
            const unsigned short* src = g.Abf + ((size_t)(b*512 + i0 + r))*512 + seg;
            *(short8*)&sm.p5.As[r*520 + seg]      = *(const short8*)src;
            *(short8*)&sm.p5.As[r*520 + seg + 8]  = *(const short8*)(src + 8);
            *(short8*)&sm.p5.As[r*520 + seg + 16] = *(const short8*)(src + 16);
            *(short8*)&sm.p5.As[r*520 + seg + 24] = *(const short8*)(src + 24);
        }
        __syncthreads();

        f32x4 acc = {};
        const unsigned short* gbase = g.G1T + ((size_t)(b*64 + w*16 + (lane&15)))*512 + (lane>>4)*8;
        int aoff = (lane&15)*520 + (lane>>4)*8;
        #pragma unroll 4
        for (int k0 = 0; k0 < 512; k0 += 32) {
            short8 af = *(const short8*)&sm.p5.As[aoff + k0];
            short8 bf = *(const short8*)(gbase + k0);
            acc = __builtin_amdgcn_mfma_f32_16x16x32_bf16(af, bf, acc, 0,0,0);
        }
        {
            int cc = w*16 + (lane&15);
            float gb = g.gc1_b[cc];
            #pragma unroll
            for (int r = 0; r < 4; ++r)
                sm.p5.xg[(lane>>4)*4 + r][cc] = fmaxf(acc[r] + gb, 0.f);
        }
        __syncthreads();

        if (tid < 160) {
            int row = tid/10, sx = tid%10;
            float a = 0.f;
            #pragma unroll
            for (int c = 0; c < 64; ++c) a += sm.p5.xg[row][c]*g.gc2_w[c*10 + sx];
            g.zT[((size_t)(b*10) + sx)*512 + i0 + row] = a;
        }
    }
    grid.sync();

    // ================= Phase 6: out = relu(Abf@zT + gc2_b).out_w + tdot =================
    {
        int s = bid*4 + w;
        int b = s >> 9;

        short8 av = *(const short8*)(g.Abf + (size_t)s*512 + lane*8);
        float a[8];
        #pragma unroll
        for (int q = 0; q < 8; ++q) a[q] = bf2f((unsigned short)av[q]);

        float acc[10];
        #pragma unroll
        for (int sx = 0; sx < 10; ++sx) {
            const float* zr = g.zT + ((size_t)(b*10) + sx)*512 + lane*8;
            float4 z0 = *(const float4*)zr;
            float4 z1 = *(const float4*)(zr + 4);
            acc[sx] = a[0]*z0.x + a[1]*z0.y + a[2]*z0.z + a[3]*z0.w
                    + a[4]*z1.x + a[5]*z1.y + a[6]*z1.z + a[7]*z1.w;
        }
        #pragma unroll
        for (int sx = 0; sx < 10; ++sx)
            #pragma unroll
            for (int off = 32; off; off >>= 1) acc[sx] += __shfl_down(acc[sx], off);
        if (lane == 0) {
            float o = g.tdot[s];
            #pragma unroll
            for (int sx = 0; sx < 10; ++sx)
                o += fmaxf(acc[sx] + g.gc2_b[sx], 0.f) * g.out_w[sx];
            g.out[s] = o;
        }
    }
}

extern "C" void kernel_launch(void* const* d_in, const int* in_sizes, int n_in,
                              void* d_out, int out_size, void* d_ws, size_t ws_size,
                              hipStream_t stream) {
    float* ws = (float*)d_ws;
    MP g;
    g.x       = (const float*)d_in[0];
    g.W_ih    = (const float*)d_in[1];
    g.W_hh    = (const float*)d_in[2];
    g.b_ih    = (const float*)d_in[3];
    g.b_hh    = (const float*)d_in[4];
    g.W1      = (const float*)d_in[5];
    g.b1      = (const float*)d_in[6];
    g.W2      = (const float*)d_in[7];
    g.V       = (const float*)d_in[8];
    g.bv      = (const float*)d_in[9];
    g.Wb      = (const float*)d_in[10];
    g.wb      = (const float*)d_in[11];
    g.conv_w  = (const float*)d_in[12];
    g.conv_b  = (const float*)d_in[13];
    g.convl_w = (const float*)d_in[14];
    g.convl_b = (const float*)d_in[15];
    g.gc1_w   = (const float*)d_in[16];
    g.gc1_b   = (const float*)d_in[17];
    g.gc2_w   = (const float*)d_in[18];
    g.gc2_b   = (const float*)d_in[19];
    g.out_w   = (const float*)d_in[20];
    g.out_b   = (const float*)d_in[21];
    g.adj     = (const float*)d_in[22];
    g.p     = ws + OFF_P;
    g.qb    = ws + OFF_QB;
    g.tdot  = ws + OFF_TDOT;
    g.colsq = ws + OFF_COLSQ;
    g.zT    = ws + OFF_ZT;
    g.G1bf  = (unsigned short*)(ws + OFF_G1B);
    g.amxB  = (unsigned short*)(ws + OFF_AMXB);
    g.WbT   = (unsigned short*)(ws + OFF_WBT);
    g.Abf   = (unsigned short*)(ws + OFF_ABF);
    g.G1T   = (unsigned short*)(ws + OFF_G1T);
    g.out   = (float*)d_out;

    void* args[] = { &g };
    hipLaunchCooperativeKernel((const void*)mega, dim3(512), dim3(256), args, 0, stream);
}

// Round 6
// 59.363 us; speedup vs baseline: 5.9522x; 5.9522x over previous
//
#include <hip/hip_runtime.h>
#include <hip/hip_bf16.h>
#include <cstdint>
#include <cstddef>

// ---------------- ws layout (float slots) ----------------
#define OFF_P     0            // 2048*32 f32
#define OFF_QB    65536        // 2048*32 f32
#define OFF_TDOT  131072       // 2048 f32
#define OFF_COLSQ 133120       // 2048 f32
#define OFF_ZT    135168       // 4*10*512 f32
#define OFF_AMXB  155648       // 4*512*512 bf16 (524288 float slots)
#define OFF_ABF   679936       // 4*512*512 bf16
#define OFF_G1T   1204224      // 4*64*512 bf16 (65536 float slots)

typedef __attribute__((ext_vector_type(8))) short short8;
typedef __attribute__((ext_vector_type(8))) unsigned short ushort8;
typedef __attribute__((ext_vector_type(4))) float f32x4;

__device__ inline unsigned short f2bf(float f) {
    unsigned u = __builtin_bit_cast(unsigned, f);
    unsigned r = u + 0x7FFFu + ((u >> 16) & 1u);
    return (unsigned short)(r >> 16);
}
__device__ inline float bf2f(unsigned short s) {
    unsigned u = ((unsigned)s) << 16;
    return __builtin_bit_cast(float, u);
}
__device__ inline float tanh_fast(float x) {
    return 1.f - 2.f/(__expf(2.f*x) + 1.f);
}

// ============ K1: RNN + p/q + convs + G1T(bf16, direct transposed write) + tdot ============
// All LDS wave-private -> NO __syncthreads (intra-wave lgkmcnt ordering).
__global__ __launch_bounds__(256) void k1_rnn(
    const float* __restrict__ x, const float* __restrict__ W_ih,
    const float* __restrict__ W_hh, const float* __restrict__ b_ih,
    const float* __restrict__ b_hh, const float* __restrict__ W1,
    const float* __restrict__ b1, const float* __restrict__ W2,
    const float* __restrict__ conv_w, const float* __restrict__ conv_b,
    const float* __restrict__ convl_w, const float* __restrict__ convl_b,
    const float* __restrict__ gc1_w, const float* __restrict__ out_w,
    const float* __restrict__ out_b,
    float* __restrict__ p_out, float* __restrict__ qb_out,
    unsigned short* __restrict__ G1T, float* __restrict__ tdot,
    float* __restrict__ colsq)
{
    __shared__ float h_sh[4][64];
    __shared__ float xt_sh[4][20];
    __shared__ float rl_sh[4][30];
    int tid = threadIdx.x;
    int w = tid >> 6, lane = tid & 63;
    int s = blockIdx.x * 4 + w;       // sequence id, 0..2047
    int b = s >> 9, m = s & 511;

    if (blockIdx.x < 8) colsq[blockIdx.x * 256 + tid] = 0.f;   // replaces memset

    if (lane < 20) xt_sh[w][lane] = x[(b*20 + lane)*512 + m];

    float wrow[64];
    const float* wr = W_hh + lane*64;
    #pragma unroll
    for (int k4 = 0; k4 < 16; ++k4) {
        float4 v = reinterpret_cast<const float4*>(wr)[k4];
        wrow[4*k4+0]=v.x; wrow[4*k4+1]=v.y; wrow[4*k4+2]=v.z; wrow[4*k4+3]=v.w;
    }
    float wih = W_ih[lane], bih = b_ih[lane], bhh = b_hh[lane];
    h_sh[w][lane] = 0.f;
    float h = 0.f;

    // convs first (independent of h) so their latency overlaps the RNN chain
    if (lane < 10) {
        float acc = conv_b[lane];
        #pragma unroll
        for (int t = 0; t < 20; ++t) acc += conv_w[lane*20+t]*xt_sh[w][t];
        rl_sh[w][3*lane] = fmaxf(acc, 0.f);
    } else if (lane < 30) {
        int idx = lane-10, j = idx>>1, oo = idx&1;
        float acc = convl_b[j];
        #pragma unroll
        for (int t = 0; t < 10; ++t) acc += convl_w[j*10+t]*xt_sh[w][oo+2*t];
        rl_sh[w][3*j+1+oo] = fmaxf(acc, 0.f);
    }

    for (int t = 0; t < 20; ++t) {
        float acc = xt_sh[w][t]*wih + bih + bhh;
        #pragma unroll
        for (int k = 0; k < 64; ++k) acc += wrow[k]*h_sh[w][k];
        h = tanh_fast(acc);
        h_sh[w][lane] = h;
    }

    // temporal part of output head (+ out_b folded here)
    float td = h * out_w[10 + lane];
    #pragma unroll
    for (int off = 32; off; off >>= 1) td += __shfl_down(td, off);
    if (lane == 0) tdot[s] = td + out_b[0];

    // p (lanes 0..31) / q+b1 (lanes 32..63)
    if (lane < 32) {
        const float* w1r = W1 + lane*64;
        float acc = 0.f;
        #pragma unroll
        for (int k = 0; k < 64; ++k) acc += w1r[k]*h_sh[w][k];
        p_out[s*32 + lane] = acc;
    } else {
        int i = lane - 32;
        const float* w2r = W2 + i*64;
        float acc = 0.f;
        #pragma unroll
        for (int k = 0; k < 64; ++k) acc += w2r[k]*h_sh[w][k];
        qb_out[s*32 + i] = acc + b1[i];
    }

    // G1 = relu(r_l) @ gc1_w  -> transposed write G1T[b][c=lane][m]
    float g = 0.f;
    #pragma unroll
    for (int t = 0; t < 30; ++t) g += rl_sh[w][t]*gc1_w[t*64 + lane];
    G1T[((size_t)(b*64 + lane))*512 + m] = f2bf(g);
}

// ============ K2a: amxB = bf16(V . elu(p_i + qb_j) + bv) ; column sumsq ============
__global__ __launch_bounds__(256) void k2_amx(
    const float* __restrict__ p, const float* __restrict__ qb,
    const float* __restrict__ V, const float* __restrict__ bv,
    unsigned short* __restrict__ amxB, float* __restrict__ colsq)
{
    __shared__ float p_sh[32*36], q_sh[32*36], v_sh[32], sq_sh[32*17];
    int t = threadIdx.x;
    int b = blockIdx.z, i0 = blockIdx.y*32, j0 = blockIdx.x*32;
    {
        int r = t >> 3, c4 = (t & 7)*4;
        *(float4*)&p_sh[r*36 + c4] = *(const float4*)(p  + (size_t)(b*512 + i0 + r)*32 + c4);
        *(float4*)&q_sh[r*36 + c4] = *(const float4*)(qb + (size_t)(b*512 + j0 + r)*32 + c4);
    }
    if (t < 32) v_sh[t] = V[t];
    __syncthreads();

    int ti = t >> 4, tj = t & 15;   // rows {ti, ti+16}, cols {tj, tj+16}
    float bv0 = bv[0];
    float a00 = bv0, a01 = bv0, a10 = bv0, a11 = bv0;
    #pragma unroll
    for (int h = 0; h < 32; ++h) {
        float p0 = p_sh[ti*36 + h], p1 = p_sh[(ti+16)*36 + h];
        float q0 = q_sh[tj*36 + h], q1 = q_sh[(tj+16)*36 + h];
        float vh = v_sh[h];
        float x00 = p0+q0, x01 = p0+q1, x10 = p1+q0, x11 = p1+q1;
        float e00 = x00 > 0.f ? x00 : __expf(x00)-1.f;
        float e01 = x01 > 0.f ? x01 : __expf(x01)-1.f;
        float e10 = x10 > 0.f ? x10 : __expf(x10)-1.f;
        float e11 = x11 > 0.f ? x11 : __expf(x11)-1.f;
        a00 += vh*e00; a01 += vh*e01; a10 += vh*e10; a11 += vh*e11;
    }
    size_t base0 = ((size_t)(b*512 + i0 + ti))*512 + j0;
    size_t base1 = ((size_t)(b*512 + i0 + ti + 16))*512 + j0;
    amxB[base0 + tj]      = f2bf(a00);
    amxB[base0 + tj + 16] = f2bf(a01);
    amxB[base1 + tj]      = f2bf(a10);
    amxB[base1 + tj + 16] = f2bf(a11);

    sq_sh[tj*17 + ti]      = a00*a00 + a10*a10;
    sq_sh[(tj+16)*17 + ti] = a01*a01 + a11*a11;
    __syncthreads();
    if (t < 32) {
        float ssum = 0.f;
        #pragma unroll
        for (int r = 0; r < 16; ++r) ssum += sq_sh[t*17 + r];
        atomicAdd(&colsq[b*512 + j0 + t], ssum);
    }
}

// ============ K3a: S = amx@diag(invn)@Wb; B-fragments gathered from Wb f32 + scaled inline ============
__global__ __launch_bounds__(64) void k3a_mfma(
    const unsigned short* __restrict__ amxB, const float* __restrict__ Wb,
    const float* __restrict__ colsq, const float* __restrict__ wb,
    const float* __restrict__ adj, unsigned short* __restrict__ Abf)
{
    int lane = threadIdx.x;
    int b = blockIdx.z;
    int i0 = blockIdx.y*32, j0 = blockIdx.x*32;
    f32x4 acc[2][2] = {};

    int kslice = (lane>>4)*8;         // 0/8/16/24
    int fr = lane & 15;               // fragment row
    const unsigned short* abase = amxB + ((size_t)(b*512 + i0 + fr))*512 + kslice;
    const float* wcol = Wb + j0 + fr;             // + k*512
    const float* csq  = colsq + b*512 + kslice;   // + k0

    for (int k0 = 0; k0 < 512; k0 += 32) {
        float4 c0 = *(const float4*)(csq + k0);
        float4 c1 = *(const float4*)(csq + k0 + 4);
        float inv[8] = {
            rsqrtf(fmaxf(c0.x,1e-24f)), rsqrtf(fmaxf(c0.y,1e-24f)),
            rsqrtf(fmaxf(c0.z,1e-24f)), rsqrtf(fmaxf(c0.w,1e-24f)),
            rsqrtf(fmaxf(c1.x,1e-24f)), rsqrtf(fmaxf(c1.y,1e-24f)),
            rsqrtf(fmaxf(c1.z,1e-24f)), rsqrtf(fmaxf(c1.w,1e-24f)) };

        short8 a0 = *(const short8*)(abase + k0);
        short8 a1 = *(const short8*)(abase + 16*512 + k0);

        const float* wk = wcol + (size_t)(k0 + kslice)*512;
        short8 b0, b1;
        #pragma unroll
        for (int m = 0; m < 8; ++m) {
            b0[m] = (short)f2bf(wk[(size_t)m*512]      * inv[m]);
            b1[m] = (short)f2bf(wk[(size_t)m*512 + 16] * inv[m]);
        }

        acc[0][0] = __builtin_amdgcn_mfma_f32_16x16x32_bf16(a0, b0, acc[0][0],0,0,0);
        acc[0][1] = __builtin_amdgcn_mfma_f32_16x16x32_bf16(a0, b1, acc[0][1],0,0,0);
        acc[1][0] = __builtin_amdgcn_mfma_f32_16x16x32_bf16(a1, b0, acc[1][0],0,0,0);
        acc[1][1] = __builtin_amdgcn_mfma_f32_16x16x32_bf16(a1, b1, acc[1][1],0,0,0);
    }

    float wbs = wb[0];
    #pragma unroll
    for (int fj = 0; fj < 2; ++fj) {
        int j = j0 + fj*16 + fr;
        float inv = rsqrtf(fmaxf(colsq[b*512 + j], 1e-24f));
        #pragma unroll
        for (int fi = 0; fi < 2; ++fi)
        #pragma unroll
        for (int r = 0; r < 4; ++r) {
            int i = i0 + fi*16 + (lane>>4)*4 + r;
            float S = acc[fi][fj][r] + wbs;
            float c = 1.f/(1.f + __expf(-S));
            float aN = bf2f(amxB[((size_t)(b*512)+i)*512 + j]) * inv;
            Abf[((size_t)(b*512)+i)*512 + j] = f2bf(adj[i*512+j]*c + aN*(1.f - c));
        }
    }
}

// ============ K3b: xg = relu(Abf@G1 + gc1_b); zT = xg@gc2_w.  A in LDS, G1T direct from L2 ============
#define AS_STRIDE 520
__global__ __launch_bounds__(256) void k3b_mfma(
    const unsigned short* __restrict__ Abf, const unsigned short* __restrict__ G1T,
    const float* __restrict__ gc1_b, const float* __restrict__ gc2_w,
    float* __restrict__ zT)
{
    __shared__ __align__(16) unsigned short As[16*AS_STRIDE];
    __shared__ float xg[16][68];
    int t = threadIdx.x;
    int b = blockIdx.y, i0 = blockIdx.x*16;
    int wv = t >> 6, lane = t & 63;

    // stage 16x512 A tile (16 KB), fully coalesced
    {
        int r = t >> 4, seg = (t & 15)*32;
        const unsigned short* src = Abf + ((size_t)(b*512 + i0 + r))*512 + seg;
        *(short8*)&As[r*AS_STRIDE + seg]      = *(const short8*)src;
        *(short8*)&As[r*AS_STRIDE + seg + 8]  = *(const short8*)(src + 8);
        *(short8*)&As[r*AS_STRIDE + seg + 16] = *(const short8*)(src + 16);
        *(short8*)&As[r*AS_STRIDE + seg + 24] = *(const short8*)(src + 24);
    }
    __syncthreads();

    f32x4 acc = {};
    const unsigned short* gbase = G1T + ((size_t)(b*64 + wv*16 + (lane&15)))*512 + (lane>>4)*8;
    int aoff = (lane&15)*AS_STRIDE + (lane>>4)*8;
    #pragma unroll 4
    for (int k0 = 0; k0 < 512; k0 += 32) {
        short8 af = *(const short8*)&As[aoff + k0];
        short8 bf = *(const short8*)(gbase + k0);
        acc = __builtin_amdgcn_mfma_f32_16x16x32_bf16(af, bf, acc, 0,0,0);
    }

    // xg = relu(acc + bias) -> LDS
    {
        int cc = wv*16 + (lane&15);
        float gb = gc1_b[cc];
        #pragma unroll
        for (int r = 0; r < 4; ++r)
            xg[(lane>>4)*4 + r][cc] = fmaxf(acc[r] + gb, 0.f);
    }
    __syncthreads();

    // z = xg @ gc2_w -> zT[b][sx][i0+row]
    if (t < 160) {
        int row = t/10, sx = t%10;
        float a = 0.f;
        #pragma unroll
        for (int c = 0; c < 64; ++c) a += xg[row][c]*gc2_w[c*10 + sx];
        zT[((size_t)(b*10) + sx)*512 + i0 + row] = a;
    }
}

// ============ K4: out = relu(Abf@zT + gc2_b).out_w + tdot ; no LDS, no barriers ============
__global__ __launch_bounds__(256) void k4_out(
    const unsigned short* __restrict__ Abf, const float* __restrict__ zT,
    const float* __restrict__ gc2_b, const float* __restrict__ out_w,
    const float* __restrict__ tdot, float* __restrict__ out)
{
    int t = threadIdx.x;
    int w = t >> 6, lane = t & 63;
    int s = blockIdx.x*4 + w;       // (b,i)
    int b = s >> 9;

    short8 av = *(const short8*)(Abf + (size_t)s*512 + lane*8);
    float a[8];
    #pragma unroll
    for (int q = 0; q < 8; ++q) a[q] = bf2f((unsigned short)av[q]);

    float acc[10];
    #pragma unroll
    for (int sx = 0; sx < 10; ++sx) {
        const float* zr = zT + ((size_t)(b*10) + sx)*512 + lane*8;
        float4 z0 = *(const float4*)zr;
        float4 z1 = *(const float4*)(zr + 4);
        acc[sx] = a[0]*z0.x + a[1]*z0.y + a[2]*z0.z + a[3]*z0.w
                + a[4]*z1.x + a[5]*z1.y + a[6]*z1.z + a[7]*z1.w;
    }
    #pragma unroll
    for (int sx = 0; sx < 10; ++sx)
        #pragma unroll
        for (int off = 32; off; off >>= 1) acc[sx] += __shfl_down(acc[sx], off);
    if (lane == 0) {
        float o = tdot[s];
        #pragma unroll
        for (int sx = 0; sx < 10; ++sx)
            o += fmaxf(acc[sx] + gc2_b[sx], 0.f) * out_w[sx];
        out[s] = o;
    }
}

extern "C" void kernel_launch(void* const* d_in, const int* in_sizes, int n_in,
                              void* d_out, int out_size, void* d_ws, size_t ws_size,
                              hipStream_t stream) {
    const float* x       = (const float*)d_in[0];
    const float* W_ih    = (const float*)d_in[1];
    const float* W_hh    = (const float*)d_in[2];
    const float* b_ih    = (const float*)d_in[3];
    const float* b_hh    = (const float*)d_in[4];
    const float* W1      = (const float*)d_in[5];
    const float* b1      = (const float*)d_in[6];
    const float* W2      = (const float*)d_in[7];
    const float* V       = (const float*)d_in[8];
    const float* bv      = (const float*)d_in[9];
    const float* Wb      = (const float*)d_in[10];
    const float* wb      = (const float*)d_in[11];
    const float* conv_w  = (const float*)d_in[12];
    const float* conv_b  = (const float*)d_in[13];
    const float* convl_w = (const float*)d_in[14];
    const float* convl_b = (const float*)d_in[15];
    const float* gc1_w   = (const float*)d_in[16];
    const float* gc1_b   = (const float*)d_in[17];
    const float* gc2_w   = (const float*)d_in[18];
    const float* gc2_b   = (const float*)d_in[19];
    const float* out_w   = (const float*)d_in[20];
    const float* out_b   = (const float*)d_in[21];
    const float* adj     = (const float*)d_in[22];

    float* ws    = (float*)d_ws;
    float* p     = ws + OFF_P;
    float* qb    = ws + OFF_QB;
    float* tdot  = ws + OFF_TDOT;
    float* colsq = ws + OFF_COLSQ;
    float* zT    = ws + OFF_ZT;
    unsigned short* amxB = (unsigned short*)(ws + OFF_AMXB);
    unsigned short* Abf  = (unsigned short*)(ws + OFF_ABF);
    unsigned short* G1T  = (unsigned short*)(ws + OFF_G1T);
    float* out   = (float*)d_out;

    k1_rnn<<<dim3(512), dim3(256), 0, stream>>>(
        x, W_ih, W_hh, b_ih, b_hh, W1, b1, W2,
        conv_w, conv_b, convl_w, convl_b, gc1_w, out_w, out_b,
        p, qb, G1T, tdot, colsq);

    k2_amx<<<dim3(16,16,4), dim3(256), 0, stream>>>(p, qb, V, bv, amxB, colsq);

    k3a_mfma<<<dim3(16,16,4), dim3(64), 0, stream>>>(amxB, Wb, colsq, wb, adj, Abf);
    k3b_mfma<<<dim3(32,4), dim3(256), 0, stream>>>(Abf, G1T, gc1_b, gc2_w, zT);
    k4_out<<<dim3(512), dim3(256), 0, stream>>>(Abf, zT, gc2_b, out_w, tdot, out);
}